// Round 10
// baseline (253.932 us; speedup 1.0000x reference)
//
#include <hip/hip_runtime.h>
#include <hip/hip_bf16.h>
#include <cstdint>

// Problem constants
#define B_   4
#define S_   2048
#define SP_  2064        // S + 16 pad rows (pad rows: x == 0 -> bias-only qkv)
#define D_   1024
#define H_   16
#define MTOT (B_ * SP_)  // 8256 rows
#define NKT  33          // 64-key tiles per batch (32 full + 16-key tail)

// q is pre-scaled by 0.125 * log2(e) so softmax = exp2(q'.k) directly
#define QSCALE 0.18033688011112042f

typedef __attribute__((ext_vector_type(8))) short short8;
typedef __attribute__((ext_vector_type(4))) float floatx4;
typedef __attribute__((ext_vector_type(16))) float floatx16;
typedef __attribute__((ext_vector_type(2))) unsigned int uint2v;
typedef __attribute__((ext_vector_type(4))) unsigned int uintx4;

// fp32 -> bf16 round-to-nearest-even
static __device__ inline unsigned short f2b(float f) {
  unsigned u = __builtin_bit_cast(unsigned, f);
  u += 0x7FFFu + ((u >> 16) & 1u);
  return (unsigned short)(u >> 16);
}

// pack two fp32 -> bf16x2 word (v_cvt_pk_bf16_f32 via compiler-known path;
// NOT inline asm -- R3 NaN hazard).
static __device__ inline unsigned pk2(float a, float b) {
  __hip_bfloat162 h = __float22bfloat162_rn(make_float2(a, b));
  unsigned r;
  __builtin_memcpy(&r, &h, 4);   // a in low 16, b in high 16
  return r;
}

// async global->LDS, 16 B per lane, dest = wave-uniform base + lane*16
static __device__ inline void gl_lds16(const unsigned short* g, unsigned short* l) {
  __builtin_amdgcn_global_load_lds((__attribute__((address_space(1))) void*)(g),
                                   (__attribute__((address_space(3))) void*)(l),
                                   16, 0, 0);
}

// ---------------------------------------------------------------------------
// Merged pre-pass: cast x (fp32->bf16) + transpose/cast all six weights +
// zero-fill the kt=32 V2 tail tiles. (R9-identical)
// grid (8192 + 3072 + 64).
// ---------------------------------------------------------------------------
__global__ __launch_bounds__(256) void prep(
    const float* __restrict__ x, unsigned short* __restrict__ xh,
    const float* __restrict__ Wq,  const float* __restrict__ Wqc,
    const float* __restrict__ Wk,  const float* __restrict__ Wkc,
    const float* __restrict__ Wv,  const float* __restrict__ Wvc,
    unsigned short* __restrict__ wq2, unsigned short* __restrict__ wk2,
    unsigned short* __restrict__ wv2, unsigned short* __restrict__ v2)
{
  __shared__ float tl[32][33];
  const int t = threadIdx.x;
  int bx = blockIdx.x;

  if (bx < 8192) {           // ---- cast_x part
    const int idx = (bx * 256 + t) * 4;
    float4 v = *(const float4*)(x + idx);
    ushort4 h;
    h.x = f2b(v.x); h.y = f2b(v.y); h.z = f2b(v.z); h.w = f2b(v.w);
    *(ushort4*)(xh + idx) = h;
    return;
  }
  if (bx >= 8192 + 3072) {   // ---- V2 tail-tile zero fill (64 (b,h) tiles)
    const int z = bx - (8192 + 3072);
    unsigned short* dst = v2 + (((size_t)z * NKT + 32) << 12) + (t << 4);
    *(uint4*)dst = make_uint4(0, 0, 0, 0);
    *(uint4*)(dst + 8) = make_uint4(0, 0, 0, 0);
    return;
  }

  // ---- wcast part
  bx -= 8192;
  const int gx = bx % 96;
  const int k0 = (bx / 96) * 32;

  const float* W; unsigned short* T; int N, nx;
  if (gx < 8)       { W = Wq;  T = wq2;               nx = gx;      N = 256;  }
  else if (gx < 16) { W = Wqc; T = wq2 + 256 * 1024;  nx = gx - 8;  N = 256;  }
  else if (gx < 24) { W = Wk;  T = wk2;               nx = gx - 16; N = 256;  }
  else if (gx < 32) { W = Wkc; T = wk2 + 256 * 1024;  nx = gx - 24; N = 256;  }
  else if (gx < 64) { W = Wv;  T = wv2;               nx = gx - 32; N = 1024; }
  else              { W = Wvc; T = wv2 + 1024 * 1024; nx = gx - 64; N = 1024; }

  const int n0 = nx * 32;
  const int r  = t >> 3;
  const int c  = (t & 7) * 4;

  float4 w = *(const float4*)(W + (size_t)(k0 + r) * N + n0 + c);
  tl[r][c + 0] = w.x; tl[r][c + 1] = w.y; tl[r][c + 2] = w.z; tl[r][c + 3] = w.w;
  __syncthreads();

  ushort4 h;
  h.x = f2b(tl[c + 0][r]); h.y = f2b(tl[c + 1][r]);
  h.z = f2b(tl[c + 2][r]); h.w = f2b(tl[c + 3][r]);
  *(ushort4*)(T + (size_t)(n0 + r) * 1024 + k0 + c) = h;
}

// ---------------------------------------------------------------------------
// Merged CSS GEMM (q + k + v in ONE dispatch), v3: OCCUPANCY over pipeline
// slack. 2-buffer LDS (48 KiB) + __launch_bounds__(256,3) -> 3 blocks/CU:
// 780 blocks / 768 co-resident = 1.02 dispatch rounds (was 72 KiB -> 2/CU ->
// 1.52 rounds, second round at half occupancy). Per-tile full drain
// (__syncthreads) is absorbed by 12-wave/CU MFMA/VMEM overlap (m114).
// Keeps: T1 bijective XCD swizzle, T2 source-swizzled LDS, stage-before-
// compute, attn-ready K2/V2 tiled outputs.
// ---------------------------------------------------------------------------
__global__ __launch_bounds__(256, 3) void css_mfma2(
    const unsigned short* __restrict__ xh,
    const unsigned short* __restrict__ wq2, const float* __restrict__ bq,
    const float* __restrict__ bqc,
    const unsigned short* __restrict__ wk2, const float* __restrict__ bk,
    const float* __restrict__ bkc,
    const unsigned short* __restrict__ wv2, const float* __restrict__ bv,
    const float* __restrict__ bvc,
    unsigned short* __restrict__ qb, unsigned short* __restrict__ k2,
    unsigned short* __restrict__ v2)
{
  __shared__ __align__(16) unsigned short smem[24576];  // 49152 B (2 bufs)

  const int t = threadIdx.x;

  // T1 bijective chunked swizzle: nwg = 780 = 8*97+4 (m204 formula).
  const int hwid = blockIdx.y * 12 + blockIdx.x;
  const int xcd  = hwid & 7;
  const int idx  = hwid >> 3;
  const int wgid = (xcd < 4 ? xcd * 98 : 392 + (xcd - 4) * 97) + idx;
  const int nt = wgid % 12;
  const int m0 = (wgid / 12) << 7;

  const unsigned short* w2;
  const float *bias, *bisc;
  unsigned short* outp;
  float scl;
  int n0, mode;
  size_t mstride;
  if (nt < 2) {
    w2 = wq2; bias = bq; bisc = bqc; outp = qb; scl = QSCALE;
    n0 = nt << 7; mode = 0; mstride = (size_t)256 * 1024;
  } else if (nt < 4) {
    w2 = wk2; bias = bk; bisc = bkc; outp = k2; scl = 1.0f;
    n0 = (nt - 2) << 7; mode = 2; mstride = (size_t)256 * 1024;
  } else {
    w2 = wv2; bias = bv; bisc = bvc; outp = v2; scl = 1.0f;
    n0 = (nt - 4) << 7; mode = 1; mstride = (size_t)1024 * 1024;
  }

  // --- staging source pointers (T2 source-swizzle):
  // logical granule g = (t&3) ^ ((row>>1)&3), row = t>>2.
  const int ko_s = (((t & 3) ^ ((t >> 3) & 3)) << 3);  // swizzled col (shorts)

  const unsigned short* sA0;
  const unsigned short* sA1;
  {
    auto arow = [&](int row) -> const unsigned short* {
      const int grow = m0 + row;
      const int bb0 = grow / SP_;
      const int ss0 = grow - bb0 * SP_;
      const int r = (grow < MTOT && ss0 < S_) ? (bb0 * S_ + ss0) : 0;
      return xh + (size_t)r * D_ + ko_s;
    };
    sA0 = arow(t >> 2);
    sA1 = arow(64 + (t >> 2));
  }
  const int brow0 = t >> 2;
  const int brow1 = 64 + (t >> 2);
  const unsigned short* sB0 = w2 + (size_t)(n0 + brow0) * 1024 + ko_s;
  const unsigned short* sB1 = w2 + (size_t)(n0 + brow1) * 1024 + ko_s;
  const unsigned short* sG0 = sB0 + mstride;
  const unsigned short* sG1 = sB1 + mstride;

  const int lane = t & 63;
  const int w    = t >> 6;
  const int lo   = lane & 15;
  const int hi   = lane >> 4;
  const int wm   = (w & 1) << 6;
  const int wn   = (w >> 1) << 6;

  // fragment-read swizzle slot (loop-invariant): ((row>>1)&3)==((lo>>1)&3)
  const int sl8 = ((hi ^ ((lo >> 1) & 3)) << 3);

  floatx4 lin[4][4], gat[4][4];
#pragma unroll
  for (int i = 0; i < 4; ++i)
#pragma unroll
    for (int j = 0; j < 4; ++j) {
      lin[i][j] = (floatx4){0.f, 0.f, 0.f, 0.f};
      gat[i][j] = (floatx4){0.f, 0.f, 0.f, 0.f};
    }

  auto stage = [&](int kt, int sel) {
    const int k0 = kt << 5;
    unsigned short* dst = &smem[sel * 12288 + t * 8];   // 16 B per lane
    gl_lds16(sA0 + k0, dst);
    gl_lds16(sA1 + k0, dst + 2048);
    gl_lds16(sB0 + k0, dst + 4096);
    gl_lds16(sB1 + k0, dst + 6144);
    gl_lds16(sG0 + k0, dst + 8192);
    gl_lds16(sG1 + k0, dst + 10240);
  };

  // --- 2-buffer pipeline: stage(kt+1) in flight while computing tile kt;
  // one full drain (__syncthreads) per K-step. Occupancy (3 blocks/CU)
  // provides the cross-wave overlap.
  stage(0, 0);
  __syncthreads();

  for (int kt = 0; kt < 32; ++kt) {
    const int sel = kt & 1;
    if (kt < 31) stage(kt + 1, sel ^ 1);

    const unsigned short* Ab = &smem[sel * 12288];
    short8 ah[4];
#pragma unroll
    for (int i = 0; i < 4; ++i)
      ah[i] = *(const short8*)(Ab + (wm + i * 16 + lo) * 32 + sl8);
#pragma unroll
    for (int j = 0; j < 4; ++j) {
      const int cb = (wn + j * 16 + lo) * 32 + sl8;
      short8 bh = *(const short8*)(Ab + 4096 + cb);
      short8 gh = *(const short8*)(Ab + 8192 + cb);
#pragma unroll
      for (int i = 0; i < 4; ++i) {
        lin[i][j] = __builtin_amdgcn_mfma_f32_16x16x32_bf16(ah[i], bh, lin[i][j], 0, 0, 0);
        gat[i][j] = __builtin_amdgcn_mfma_f32_16x16x32_bf16(ah[i], gh, gat[i][j], 0, 0, 0);
      }
    }
    __syncthreads();  // reads of buf[sel] done AND stage(kt+1) drained
  }

  // ---- epilogue: stage bf16 tile in LDS, then coalesced 16 B stores
  unsigned short (*Os)[136] = reinterpret_cast<unsigned short (*)[136]>(&smem[0]);

#pragma unroll
  for (int j = 0; j < 4; ++j) {
    const int nl = wn + j * 16 + lo;
    const int n  = n0 + nl;
    const float bj = bias[n];
    const float cj = bisc[n];
#pragma unroll
    for (int i = 0; i < 4; ++i) {
      const int ml = wm + i * 16 + (hi << 2);
      unsigned short o16[4];
#pragma unroll
      for (int r = 0; r < 4; ++r) {
        const int gmr = m0 + ml + r;
        const int ssr = gmr - (gmr / SP_) * SP_;
        const bool padr = (ssr >= S_);          // x = 0 row -> bias-only
        float lv = (padr ? 0.f : lin[i][j][r]) + bj;
        float gv = (padr ? 0.f : gat[i][j][r]) + cj;
        o16[r] = f2b(scl * lv / (1.f + __expf(-gv)));
      }
      if (mode != 1) {
#pragma unroll
        for (int r = 0; r < 4; ++r) Os[ml + r][nl] = o16[r];
      } else {
        *(ushort4*)&Os[nl][ml] = make_ushort4(o16[0], o16[1], o16[2], o16[3]);
      }
    }
  }
  __syncthreads();

  // stores: 16 consecutive lanes cover one 256 B Os row-run
#pragma unroll
  for (int c = 0; c < 8; ++c) {
    const int rr = (t >> 4) + 16 * c;   // Os row
    const int cc = (t & 15) << 3;       // Os col chunk (8 shorts = 16 B)
    uint4 val = *(const uint4*)&Os[rr][cc];
    if (mode == 0) {                    // q: flat [row][256]
      const int gm = m0 + rr;
      if (gm < MTOT)
        *(uint4*)(outp + (size_t)gm * 256 + n0 + cc) = val;
    } else if (mode == 2) {             // k: K2 [b][h][kt][key][kd16]
      const int gm = m0 + rr;
      if (gm < MTOT) {
        const int vb = gm / SP_;
        const int s  = gm - vb * SP_;
        const int kt = s >> 6;
        const int key = s & 63;
        const int n  = n0 + cc;         // 8-aligned
        const int h  = n >> 4;
        const int kd = n & 15;          // 0 or 8
        *(uint4*)(outp +
                  (((size_t)((vb * 16 + h) * NKT + kt) * 64 + key) << 4) + kd) = val;
      }
    } else {                            // v: V2 [b][h][kt][d][slot][8]
      const int g = m0 + cc;            // key row, 8-aligned
      if (g < MTOT) {
        const int vb = g / SP_;
        const int s  = g - vb * SP_;
        const int kt = s >> 6;
        const int key8 = (s >> 3) & 7;
        const int dg = n0 + rr;         // h*64 + d
        const int h  = dg >> 6;
        const int d  = dg & 63;
        const int slot = key8 ^ (d & 7);
        *(uint4*)(outp + (((size_t)((vb * 16 + h) * NKT + kt)) << 12) +
                  (d << 6) + (slot << 3)) = val;
      }
    }
  }
}

// ---------------------------------------------------------------------------
// MFMA flash attention v6 (R9-identical, verified 74.5 us):
//  * VALU-tree row-sum, T5 setprio around PV MFMAs, T1 swizzle, tiled K2/V2
//    contiguous staging, 3-deep counted-vmcnt pipeline, swapped QK^T,
//    in-register softmax.
// ---------------------------------------------------------------------------
__global__ __launch_bounds__(256, 4) void attn_mfma(
    const unsigned short* __restrict__ Q,   // bf16 [MTOT][256], pre-scaled
    const unsigned short* __restrict__ K2,  // bf16 [b][h][kt][key64][kd16]
    const unsigned short* __restrict__ V2,  // bf16 [b][h][kt][d64][slot8][8]
    float* __restrict__ out)                // fp32 [B][S_][1024]
{
  // T1: contiguous 128-block chunk per XCD. Bijective: 1024 = 8*128.
  const int bx = ((blockIdx.x & 7) << 7) + (blockIdx.x >> 3);
  const int qt = bx & 15;
  const int h  = (bx >> 4) & 15;
  const int b  = bx >> 8;

  const int tid  = threadIdx.x;
  const int lane = tid & 63;
  const int w    = tid >> 6;
  const int l31  = lane & 31;
  const int h32  = lane >> 5;

  const int kbase = b * SP_;               // row base into Q
  const int hoff  = h << 4;                // head col offset (shorts)
  const int thb   = (b << 4) + h;          // (b*16 + h) tile-row base
  const int q0    = (qt << 7) + (w << 5);  // this wave's first query

  __shared__ __align__(16) unsigned short ksb[3][64 * 16];  // [key][kdim]
  __shared__ __align__(16) unsigned short vsb[3][512 * 8];  // [d][slot][8]

  // Q B-frag: B[kd = 8*h32 + j][q = l31]  (16 B contiguous per lane)
  const short8 aq =
      *(const short8*)(Q + ((size_t)(kbase + q0 + l31) << 8) + hoff + (h32 << 3));

  floatx16 z16;
#pragma unroll
  for (int r = 0; r < 16; ++r) z16[r] = 0.f;
  floatx16 Of0 = z16, Of1 = z16;
  float lsum = 0.f;

  // pre-hoisted LDS offsets (shorts); dt=1 adds 2048 ((32+l31)&7 == l31&7)
  const int ak0 = (l31 << 4) + (h32 << 3);
  const int ak1 = ((32 + l31) << 4) + (h32 << 3);
  const int rb0 = l31 << 6;
  const int sw0 = l31 & 7;
  const int v00 = rb0 + (((0 + h32) ^ sw0) << 3);  // c=0, pair 0
  const int v01 = rb0 + (((2 + h32) ^ sw0) << 3);  // c=0, pair 1
  const int v10 = rb0 + (((4 + h32) ^ sw0) << 3);  // c=1, pair 0
  const int v11 = rb0 + (((6 + h32) ^ sw0) << 3);  // c=1, pair 1

  auto stage = [&](int kt, int sel) {
    // K tile: 2 KB contiguous. Waves 0-1 only (3 VMEM/stage vs 2 for w 2-3).
    const size_t kb = ((size_t)(thb * NKT + kt)) << 10;
    if (tid < 128)
      gl_lds16(K2 + kb + (tid << 3), &ksb[sel][tid << 3]);
    // V tile: 8 KB contiguous (granule swizzle baked into V2 by css).
    const size_t vb = ((size_t)(thb * NKT + kt)) << 12;
    gl_lds16(V2 + vb + (tid << 3), &vsb[sel][tid << 3]);
    gl_lds16(V2 + vb + ((256 + tid) << 3), &vsb[sel][(256 + tid) << 3]);
  };

  auto chunk = [&](int c, bool tail8, int sel) {
    // A-frag: K[key = c*32 + l31][kd = 8*h32 + j]
    const short8 ak = *(const short8*)&ksb[sel][c ? ak1 : ak0];
    // sc[r] = S^T[key = crow(r,h32)][q = l31]
    floatx16 sc = __builtin_amdgcn_mfma_f32_32x32x16_bf16(ak, aq, z16, 0, 0, 0);

    float p[16];
#pragma unroll
    for (int r = 0; r < 16; ++r) {
      float e = __builtin_amdgcn_exp2f(sc[r]);
      p[r] = (tail8 && r >= 8) ? 0.f : e;   // tail: keys >= 16 invalid
    }

    // row-sum on VALU (15 adds; P is lane-local)
    lsum += (((p[0] + p[1]) + (p[2] + p[3])) + ((p[4] + p[5]) + (p[6] + p[7]))) +
            (((p[8] + p[9]) + (p[10] + p[11])) + ((p[12] + p[13]) + (p[14] + p[15])));

    // pack bf16 pairs; word m holds keys crow(2m..2m+1,h)
    const unsigned w0 = pk2(p[0], p[1]),   w1 = pk2(p[2], p[3]);
    const unsigned w2 = pk2(p[4], p[5]),   w3 = pk2(p[6], p[7]);
    const unsigned w4 = pk2(p[8], p[9]),   w5 = pk2(p[10], p[11]);
    const unsigned w6 = pk2(p[12], p[13]), w7 = pk2(p[14], p[15]);

    // permlane32_swap: out0 = {in0.lo | in1.lo->hi}, out1 = {in0.hi->lo | in1.hi}
    const uint2v a02 = __builtin_amdgcn_permlane32_swap(w0, w2, false, false);
    const uint2v a13 = __builtin_amdgcn_permlane32_swap(w1, w3, false, false);
    const uint2v a46 = __builtin_amdgcn_permlane32_swap(w4, w6, false, false);
    const uint2v a57 = __builtin_amdgcn_permlane32_swap(w5, w7, false, false);

    // PA frags: A[q = l31][key = kc*16 + 8*h32 + j]
    const short8 pa0 = __builtin_bit_cast(short8, (uintx4){a02[0], a13[0], a02[1], a13[1]});
    const short8 pa1 = __builtin_bit_cast(short8, (uintx4){a46[0], a57[0], a46[1], a57[1]});

    const int o0 = c ? v10 : v00;
    const int o1 = c ? v11 : v01;
    __builtin_amdgcn_s_setprio(1);      // T5: keep matrix pipe fed
    {
      const short8 bv0 = *(const short8*)&vsb[sel][o0];
      const short8 bv1 = *(const short8*)&vsb[sel][o1];
      Of0 = __builtin_amdgcn_mfma_f32_32x32x16_bf16(pa0, bv0, Of0, 0, 0, 0);
      Of0 = __builtin_amdgcn_mfma_f32_32x32x16_bf16(pa1, bv1, Of0, 0, 0, 0);
    }
    {
      const short8 bv0 = *(const short8*)&vsb[sel][o0 + 2048];
      const short8 bv1 = *(const short8*)&vsb[sel][o1 + 2048];
      Of1 = __builtin_amdgcn_mfma_f32_32x32x16_bf16(pa0, bv0, Of1, 0, 0, 0);
      Of1 = __builtin_amdgcn_mfma_f32_32x32x16_bf16(pa1, bv1, Of1, 0, 0, 0);
    }
    __builtin_amdgcn_s_setprio(0);
  };

  // --- 3-deep pipeline with counted vmcnt (waves 0-1: 3 VMEM/stage, 2-3: 2).
  stage(0, 0);
  stage(1, 1);
  if (w < 2) asm volatile("s_waitcnt vmcnt(3)" ::: "memory");
  else       asm volatile("s_waitcnt vmcnt(2)" ::: "memory");
  __builtin_amdgcn_s_barrier();

  for (int kt = 0; kt < 32; ++kt) {
    const int sel = kt % 3;
    if (kt < 31) stage(kt + 2, (kt + 2) % 3);
    chunk(0, false, sel);
    chunk(1, false, sel);
    if (kt < 31) {
      if (w < 2) asm volatile("s_waitcnt vmcnt(3)" ::: "memory");
      else       asm volatile("s_waitcnt vmcnt(2)" ::: "memory");
    } else {
      asm volatile("s_waitcnt vmcnt(0)" ::: "memory");
    }
    __builtin_amdgcn_s_barrier();
  }
  chunk(0, true, 2);  // tail tile 32 (32 % 3 == 2; keys 2048..2063 valid)

  // epilogue: combine key-half partial sums, transpose 1/l into C-layout
  lsum += __shfl_xor(lsum, 32);
  const float inv = 1.f / lsum;   // per q = l31, replicated across halves
#pragma unroll
  for (int r = 0; r < 16; ++r) {
    const int cr = (r & 3) + ((r >> 2) << 3) + (h32 << 2);  // crow(r,h32)
    const float invr = __shfl(inv, cr);
    const int qg = q0 + cr;
    float* op = out + (((size_t)(b * S_ + qg)) << 10) + (h << 6) + l31;
    op[0]  = Of0[r] * invr;
    op[32] = Of1[r] * invr;
  }
}

// ---------------------------------------------------------------------------
extern "C" void kernel_launch(void* const* d_in, const int* in_sizes, int n_in,
                              void* d_out, int out_size, void* d_ws, size_t ws_size,
                              hipStream_t stream) {
  (void)in_sizes; (void)n_in; (void)out_size; (void)ws_size;

  const float* x   = (const float*)d_in[0];
  const float* Wq  = (const float*)d_in[1];
  const float* bq  = (const float*)d_in[2];
  const float* Wqc = (const float*)d_in[3];
  const float* bqc = (const float*)d_in[4];
  const float* Wk  = (const float*)d_in[5];
  const float* bk  = (const float*)d_in[6];
  const float* Wkc = (const float*)d_in[7];
  const float* bkc = (const float*)d_in[8];
  const float* Wv  = (const float*)d_in[9];
  const float* bv  = (const float*)d_in[10];
  const float* Wvc = (const float*)d_in[11];
  const float* bvc = (const float*)d_in[12];
  float* out = (float*)d_out;

  // workspace layout (ushort units), total ~49 MB
  unsigned short* qb  = (unsigned short*)d_ws;                 // [MTOT][256]
  unsigned short* k2  = qb + (size_t)MTOT * 256;               // [64][NKT][64][16]
  unsigned short* v2  = k2 + (size_t)B_ * H_ * NKT * 1024;     // [64][NKT][4096]
  unsigned short* xh  = v2 + (size_t)B_ * H_ * NKT * 4096;     // [B*S][1024]
  unsigned short* wq2 = xh + (size_t)B_ * S_ * D_;             // [2][256][1024]
  unsigned short* wk2 = wq2 + (size_t)2 * 256 * 1024;
  unsigned short* wv2 = wk2 + (size_t)2 * 256 * 1024;          // [2][1024][1024]

  dim3 blk(256);

  // merged cast_x + weight transpose + V2 tail zero-fill (one dispatch)
  prep<<<dim3(8192 + 3072 + 64), blk, 0, stream>>>(
      x, xh, Wq, Wqc, Wk, Wkc, Wv, Wvc, wq2, wk2, wv2, v2);

  // merged q+k+v CSS GEMM: nt 0-1 -> q (pre-scaled), 2-3 -> k (K2 tiled),
  // 4-11 -> v (V2 tiled)
  css_mfma2<<<dim3(12, 65), blk, 0, stream>>>(xh, wq2, bq, bqc, wk2, bk, bkc,
                                              wv2, bv, bvc, qb, k2, v2);

  attn_mfma<<<B_ * H_ * (S_ / 128), blk, 0, stream>>>(qb, k2, v2, out);
}

// Round 11
// 239.041 us; speedup vs baseline: 1.0623x; 1.0623x over previous
//
#include <hip/hip_runtime.h>
#include <hip/hip_bf16.h>
#include <cstdint>

// Problem constants
#define B_   4
#define S_   2048
#define SP_  2064        // S + 16 pad rows (pad rows: x == 0 -> bias-only qkv)
#define D_   1024
#define H_   16
#define MTOT (B_ * SP_)  // 8256 rows
#define NKT  33          // 64-key tiles per batch (32 full + 16-key tail)

// q is pre-scaled by 0.125 * log2(e) so softmax = exp2(q'.k) directly
#define QSCALE 0.18033688011112042f

typedef __attribute__((ext_vector_type(8))) short short8;
typedef __attribute__((ext_vector_type(4))) float floatx4;
typedef __attribute__((ext_vector_type(16))) float floatx16;
typedef __attribute__((ext_vector_type(2))) unsigned int uint2v;
typedef __attribute__((ext_vector_type(4))) unsigned int uintx4;

// fp32 -> bf16 round-to-nearest-even
static __device__ inline unsigned short f2b(float f) {
  unsigned u = __builtin_bit_cast(unsigned, f);
  u += 0x7FFFu + ((u >> 16) & 1u);
  return (unsigned short)(u >> 16);
}

// pack two fp32 -> bf16x2 word (v_cvt_pk_bf16_f32 via compiler-known path;
// NOT inline asm -- R3 NaN hazard).
static __device__ inline unsigned pk2(float a, float b) {
  __hip_bfloat162 h = __float22bfloat162_rn(make_float2(a, b));
  unsigned r;
  __builtin_memcpy(&r, &h, 4);   // a in low 16, b in high 16
  return r;
}

// async global->LDS, 16 B per lane, dest = wave-uniform base + lane*16
static __device__ inline void gl_lds16(const unsigned short* g, unsigned short* l) {
  __builtin_amdgcn_global_load_lds((__attribute__((address_space(1))) void*)(g),
                                   (__attribute__((address_space(3))) void*)(l),
                                   16, 0, 0);
}

// ---------------------------------------------------------------------------
// Merged pre-pass v2 (efficiency rewrite; R10 post-mortem: prep+overhead was
// ~88 us -- the old version used 11328 tiny blocks and 8 B scattered
// transpose stores):
//  * cast_x: 2048 fat blocks, 4 float4/thread grid-stride, fully coalesced.
//  * wcast: 768 blocks, 128k x 32n tile per block; output rows are 256 B
//    CONTIGUOUS (16 shorts/thread) instead of 64 B fragments.
//  * V2 kt=32 tail zero-fill: 64 blocks (unchanged).
// grid (2048 + 768 + 64).
// ---------------------------------------------------------------------------
__global__ __launch_bounds__(256) void prep(
    const float* __restrict__ x, unsigned short* __restrict__ xh,
    const float* __restrict__ Wq,  const float* __restrict__ Wqc,
    const float* __restrict__ Wk,  const float* __restrict__ Wkc,
    const float* __restrict__ Wv,  const float* __restrict__ Wvc,
    unsigned short* __restrict__ wq2, unsigned short* __restrict__ wk2,
    unsigned short* __restrict__ wv2, unsigned short* __restrict__ v2)
{
  const int t = threadIdx.x;
  int bx = blockIdx.x;

  if (bx < 2048) {           // ---- cast_x: 8M floats, 4 float4 per thread
    const float4* xv = (const float4*)x;
    ushort4* xo = (ushort4*)xh;
    int i = bx * 256 + t;    // float4 index; stride 2048*256 per iteration
#pragma unroll
    for (int k = 0; k < 4; ++k) {
      float4 v = xv[i];
      ushort4 h4;
      h4.x = f2b(v.x); h4.y = f2b(v.y); h4.z = f2b(v.z); h4.w = f2b(v.w);
      xo[i] = h4;
      i += 2048 * 256;
    }
    return;
  }
  if (bx >= 2048 + 768) {    // ---- V2 tail-tile zero fill (64 (b,h) tiles)
    const int z = bx - (2048 + 768);
    unsigned short* dst = v2 + (((size_t)z * NKT + 32) << 12) + (t << 4);
    *(uint4*)dst = make_uint4(0, 0, 0, 0);
    *(uint4*)(dst + 8) = make_uint4(0, 0, 0, 0);
    return;
  }

  // ---- wcast: transpose W[1024][N] fp32 -> T[N][1024] bf16, 128x32 tiles
  bx -= 2048;
  const int gx = bx % 96;
  const int k0 = (bx / 96) * 128;   // 8 k-blocks of 128

  const float* W; unsigned short* T; int N, nx;
  if (gx < 8)       { W = Wq;  T = wq2;               nx = gx;      N = 256;  }
  else if (gx < 16) { W = Wqc; T = wq2 + 256 * 1024;  nx = gx - 8;  N = 256;  }
  else if (gx < 24) { W = Wk;  T = wk2;               nx = gx - 16; N = 256;  }
  else if (gx < 32) { W = Wkc; T = wk2 + 256 * 1024;  nx = gx - 24; N = 256;  }
  else if (gx < 64) { W = Wv;  T = wv2;               nx = gx - 32; N = 1024; }
  else              { W = Wvc; T = wv2 + 1024 * 1024; nx = gx - 64; N = 1024; }

  const int n0 = nx * 32;

  __shared__ float tl[128][33];
  const int r = t >> 3;             // 0..31
  const int c = (t & 7) * 4;        // 0..28
#pragma unroll
  for (int i = 0; i < 4; ++i) {
    float4 wv = *(const float4*)(W + (size_t)(k0 + r + i * 32) * N + n0 + c);
    tl[r + i * 32][c + 0] = wv.x; tl[r + i * 32][c + 1] = wv.y;
    tl[r + i * 32][c + 2] = wv.z; tl[r + i * 32][c + 3] = wv.w;
  }
  __syncthreads();

  // output: 32 rows (n) x 128 cols (k); 16 shorts (32 B) per thread,
  // 8 threads cover one 256 B row contiguously.
  const int r2 = t >> 3;            // out row 0..31
  const int c2 = (t & 7) * 16;      // out col base
  unsigned short o[16];
#pragma unroll
  for (int j = 0; j < 16; ++j) o[j] = f2b(tl[c2 + j][r2]);
  unsigned short* dst = T + (size_t)(n0 + r2) * 1024 + k0 + c2;
  *(uint4*)dst = *(const uint4*)&o[0];
  *(uint4*)(dst + 8) = *(const uint4*)&o[8];
}

// ---------------------------------------------------------------------------
// Merged CSS GEMM (q + k + v in ONE dispatch) -- R9 version verbatim
// (72 KiB triple-buffer + counted vmcnt; R10's 2-buffer/48KB regressed to
// 91 us with per-tile drain stalls -- reverted).
// ---------------------------------------------------------------------------
__global__ __launch_bounds__(256, 2) void css_mfma2(
    const unsigned short* __restrict__ xh,
    const unsigned short* __restrict__ wq2, const float* __restrict__ bq,
    const float* __restrict__ bqc,
    const unsigned short* __restrict__ wk2, const float* __restrict__ bk,
    const float* __restrict__ bkc,
    const unsigned short* __restrict__ wv2, const float* __restrict__ bv,
    const float* __restrict__ bvc,
    unsigned short* __restrict__ qb, unsigned short* __restrict__ k2,
    unsigned short* __restrict__ v2)
{
  __shared__ __align__(16) unsigned short smem[36864];  // 73728 B (3 bufs)

  const int t = threadIdx.x;

  // T1 bijective chunked swizzle: nwg = 780 = 8*97+4 (m204 formula).
  const int hwid = blockIdx.y * 12 + blockIdx.x;
  const int xcd  = hwid & 7;
  const int idx  = hwid >> 3;
  const int wgid = (xcd < 4 ? xcd * 98 : 392 + (xcd - 4) * 97) + idx;
  const int nt = wgid % 12;
  const int m0 = (wgid / 12) << 7;

  const unsigned short* w2;
  const float *bias, *bisc;
  unsigned short* outp;
  float scl;
  int n0, mode;
  size_t mstride;
  if (nt < 2) {
    w2 = wq2; bias = bq; bisc = bqc; outp = qb; scl = QSCALE;
    n0 = nt << 7; mode = 0; mstride = (size_t)256 * 1024;
  } else if (nt < 4) {
    w2 = wk2; bias = bk; bisc = bkc; outp = k2; scl = 1.0f;
    n0 = (nt - 2) << 7; mode = 2; mstride = (size_t)256 * 1024;
  } else {
    w2 = wv2; bias = bv; bisc = bvc; outp = v2; scl = 1.0f;
    n0 = (nt - 4) << 7; mode = 1; mstride = (size_t)1024 * 1024;
  }

  // --- staging source pointers (T2 source-swizzle):
  // logical granule g = (t&3) ^ ((row>>1)&3), row = t>>2.
  const int ko_s = (((t & 3) ^ ((t >> 3) & 3)) << 3);  // swizzled col (shorts)

  const unsigned short* sA0;
  const unsigned short* sA1;
  {
    auto arow = [&](int row) -> const unsigned short* {
      const int grow = m0 + row;
      const int bb0 = grow / SP_;
      const int ss0 = grow - bb0 * SP_;
      const int r = (grow < MTOT && ss0 < S_) ? (bb0 * S_ + ss0) : 0;
      return xh + (size_t)r * D_ + ko_s;
    };
    sA0 = arow(t >> 2);
    sA1 = arow(64 + (t >> 2));
  }
  const int brow0 = t >> 2;
  const int brow1 = 64 + (t >> 2);
  const unsigned short* sB0 = w2 + (size_t)(n0 + brow0) * 1024 + ko_s;
  const unsigned short* sB1 = w2 + (size_t)(n0 + brow1) * 1024 + ko_s;
  const unsigned short* sG0 = sB0 + mstride;
  const unsigned short* sG1 = sB1 + mstride;

  const int lane = t & 63;
  const int w    = t >> 6;
  const int lo   = lane & 15;
  const int hi   = lane >> 4;
  const int wm   = (w & 1) << 6;
  const int wn   = (w >> 1) << 6;

  // fragment-read swizzle slot (loop-invariant): ((row>>1)&3)==((lo>>1)&3)
  const int sl8 = ((hi ^ ((lo >> 1) & 3)) << 3);

  floatx4 lin[4][4], gat[4][4];
#pragma unroll
  for (int i = 0; i < 4; ++i)
#pragma unroll
    for (int j = 0; j < 4; ++j) {
      lin[i][j] = (floatx4){0.f, 0.f, 0.f, 0.f};
      gat[i][j] = (floatx4){0.f, 0.f, 0.f, 0.f};
    }

  auto stage = [&](int kt, int sel) {
    const int k0 = kt << 5;
    unsigned short* dst = &smem[sel * 12288 + t * 8];   // 16 B per lane
    gl_lds16(sA0 + k0, dst);
    gl_lds16(sA1 + k0, dst + 2048);
    gl_lds16(sB0 + k0, dst + 4096);
    gl_lds16(sB1 + k0, dst + 6144);
    gl_lds16(sG0 + k0, dst + 8192);
    gl_lds16(sG1 + k0, dst + 10240);
  };

  // --- 3-deep pipeline, counted vmcnt (every wave issues 6 VMEM/stage).
  stage(0, 0);
  stage(1, 1);
  asm volatile("s_waitcnt vmcnt(6)" ::: "memory");
  __builtin_amdgcn_s_barrier();

  for (int kt = 0; kt < 32; ++kt) {
    const int sel = kt % 3;
    if (kt < 30) stage(kt + 2, (kt + 2) % 3);

    const unsigned short* Ab = &smem[sel * 12288];
    short8 ah[4];
#pragma unroll
    for (int i = 0; i < 4; ++i)
      ah[i] = *(const short8*)(Ab + (wm + i * 16 + lo) * 32 + sl8);
#pragma unroll
    for (int j = 0; j < 4; ++j) {
      const int cb = (wn + j * 16 + lo) * 32 + sl8;
      short8 bh = *(const short8*)(Ab + 4096 + cb);
      short8 gh = *(const short8*)(Ab + 8192 + cb);
#pragma unroll
      for (int i = 0; i < 4; ++i) {
        lin[i][j] = __builtin_amdgcn_mfma_f32_16x16x32_bf16(ah[i], bh, lin[i][j], 0, 0, 0);
        gat[i][j] = __builtin_amdgcn_mfma_f32_16x16x32_bf16(ah[i], gh, gat[i][j], 0, 0, 0);
      }
    }

    asm volatile("s_waitcnt lgkmcnt(0)" ::: "memory");
    if (kt < 30) asm volatile("s_waitcnt vmcnt(6)" ::: "memory");
    else         asm volatile("s_waitcnt vmcnt(0)" ::: "memory");
    __builtin_amdgcn_s_barrier();
  }

  // ---- epilogue: stage bf16 tile in LDS, then coalesced 16 B stores
  __syncthreads();  // compiler-visible barrier before Os overlays buffers
  unsigned short (*Os)[136] = reinterpret_cast<unsigned short (*)[136]>(&smem[0]);

#pragma unroll
  for (int j = 0; j < 4; ++j) {
    const int nl = wn + j * 16 + lo;
    const int n  = n0 + nl;
    const float bj = bias[n];
    const float cj = bisc[n];
#pragma unroll
    for (int i = 0; i < 4; ++i) {
      const int ml = wm + i * 16 + (hi << 2);
      unsigned short o16[4];
#pragma unroll
      for (int r = 0; r < 4; ++r) {
        const int gmr = m0 + ml + r;
        const int ssr = gmr - (gmr / SP_) * SP_;
        const bool padr = (ssr >= S_);          // x = 0 row -> bias-only
        float lv = (padr ? 0.f : lin[i][j][r]) + bj;
        float gv = (padr ? 0.f : gat[i][j][r]) + cj;
        o16[r] = f2b(scl * lv / (1.f + __expf(-gv)));
      }
      if (mode != 1) {
#pragma unroll
        for (int r = 0; r < 4; ++r) Os[ml + r][nl] = o16[r];
      } else {
        *(ushort4*)&Os[nl][ml] = make_ushort4(o16[0], o16[1], o16[2], o16[3]);
      }
    }
  }
  __syncthreads();

  // stores: 16 consecutive lanes cover one 256 B Os row-run
#pragma unroll
  for (int c = 0; c < 8; ++c) {
    const int rr = (t >> 4) + 16 * c;   // Os row
    const int cc = (t & 15) << 3;       // Os col chunk (8 shorts = 16 B)
    uint4 val = *(const uint4*)&Os[rr][cc];
    if (mode == 0) {                    // q: flat [row][256]
      const int gm = m0 + rr;
      if (gm < MTOT)
        *(uint4*)(outp + (size_t)gm * 256 + n0 + cc) = val;
    } else if (mode == 2) {             // k: K2 [b][h][kt][key][kd16]
      const int gm = m0 + rr;
      if (gm < MTOT) {
        const int vb = gm / SP_;
        const int s  = gm - vb * SP_;
        const int kt = s >> 6;
        const int key = s & 63;
        const int n  = n0 + cc;         // 8-aligned
        const int h  = n >> 4;
        const int kd = n & 15;          // 0 or 8
        *(uint4*)(outp +
                  (((size_t)((vb * 16 + h) * NKT + kt) * 64 + key) << 4) + kd) = val;
      }
    } else {                            // v: V2 [b][h][kt][d][slot][8]
      const int g = m0 + cc;            // key row, 8-aligned
      if (g < MTOT) {
        const int vb = g / SP_;
        const int s  = g - vb * SP_;
        const int kt = s >> 6;
        const int key8 = (s >> 3) & 7;
        const int dg = n0 + rr;         // h*64 + d
        const int h  = dg >> 6;
        const int d  = dg & 63;
        const int slot = key8 ^ (d & 7);
        *(uint4*)(outp + (((size_t)((vb * 16 + h) * NKT + kt)) << 12) +
                  (d << 6) + (slot << 3)) = val;
      }
    }
  }
}

// ---------------------------------------------------------------------------
// MFMA flash attention v6 (R9-identical, verified 74.5 us):
//  * VALU-tree row-sum, T5 setprio around PV MFMAs, T1 swizzle, tiled K2/V2
//    contiguous staging, 3-deep counted-vmcnt pipeline, swapped QK^T,
//    in-register softmax.
// ---------------------------------------------------------------------------
__global__ __launch_bounds__(256, 4) void attn_mfma(
    const unsigned short* __restrict__ Q,   // bf16 [MTOT][256], pre-scaled
    const unsigned short* __restrict__ K2,  // bf16 [b][h][kt][key64][kd16]
    const unsigned short* __restrict__ V2,  // bf16 [b][h][kt][d64][slot8][8]
    float* __restrict__ out)                // fp32 [B][S_][1024]
{
  // T1: contiguous 128-block chunk per XCD. Bijective: 1024 = 8*128.
  const int bx = ((blockIdx.x & 7) << 7) + (blockIdx.x >> 3);
  const int qt = bx & 15;
  const int h  = (bx >> 4) & 15;
  const int b  = bx >> 8;

  const int tid  = threadIdx.x;
  const int lane = tid & 63;
  const int w    = tid >> 6;
  const int l31  = lane & 31;
  const int h32  = lane >> 5;

  const int kbase = b * SP_;               // row base into Q
  const int hoff  = h << 4;                // head col offset (shorts)
  const int thb   = (b << 4) + h;          // (b*16 + h) tile-row base
  const int q0    = (qt << 7) + (w << 5);  // this wave's first query

  __shared__ __align__(16) unsigned short ksb[3][64 * 16];  // [key][kdim]
  __shared__ __align__(16) unsigned short vsb[3][512 * 8];  // [d][slot][8]

  // Q B-frag: B[kd = 8*h32 + j][q = l31]  (16 B contiguous per lane)
  const short8 aq =
      *(const short8*)(Q + ((size_t)(kbase + q0 + l31) << 8) + hoff + (h32 << 3));

  floatx16 z16;
#pragma unroll
  for (int r = 0; r < 16; ++r) z16[r] = 0.f;
  floatx16 Of0 = z16, Of1 = z16;
  float lsum = 0.f;

  // pre-hoisted LDS offsets (shorts); dt=1 adds 2048 ((32+l31)&7 == l31&7)
  const int ak0 = (l31 << 4) + (h32 << 3);
  const int ak1 = ((32 + l31) << 4) + (h32 << 3);
  const int rb0 = l31 << 6;
  const int sw0 = l31 & 7;
  const int v00 = rb0 + (((0 + h32) ^ sw0) << 3);  // c=0, pair 0
  const int v01 = rb0 + (((2 + h32) ^ sw0) << 3);  // c=0, pair 1
  const int v10 = rb0 + (((4 + h32) ^ sw0) << 3);  // c=1, pair 0
  const int v11 = rb0 + (((6 + h32) ^ sw0) << 3);  // c=1, pair 1

  auto stage = [&](int kt, int sel) {
    // K tile: 2 KB contiguous. Waves 0-1 only (3 VMEM/stage vs 2 for w 2-3).
    const size_t kb = ((size_t)(thb * NKT + kt)) << 10;
    if (tid < 128)
      gl_lds16(K2 + kb + (tid << 3), &ksb[sel][tid << 3]);
    // V tile: 8 KB contiguous (granule swizzle baked into V2 by css).
    const size_t vb = ((size_t)(thb * NKT + kt)) << 12;
    gl_lds16(V2 + vb + (tid << 3), &vsb[sel][tid << 3]);
    gl_lds16(V2 + vb + ((256 + tid) << 3), &vsb[sel][(256 + tid) << 3]);
  };

  auto chunk = [&](int c, bool tail8, int sel) {
    // A-frag: K[key = c*32 + l31][kd = 8*h32 + j]
    const short8 ak = *(const short8*)&ksb[sel][c ? ak1 : ak0];
    // sc[r] = S^T[key = crow(r,h32)][q = l31]
    floatx16 sc = __builtin_amdgcn_mfma_f32_32x32x16_bf16(ak, aq, z16, 0, 0, 0);

    float p[16];
#pragma unroll
    for (int r = 0; r < 16; ++r) {
      float e = __builtin_amdgcn_exp2f(sc[r]);
      p[r] = (tail8 && r >= 8) ? 0.f : e;   // tail: keys >= 16 invalid
    }

    // row-sum on VALU (15 adds; P is lane-local)
    lsum += (((p[0] + p[1]) + (p[2] + p[3])) + ((p[4] + p[5]) + (p[6] + p[7]))) +
            (((p[8] + p[9]) + (p[10] + p[11])) + ((p[12] + p[13]) + (p[14] + p[15])));

    // pack bf16 pairs; word m holds keys crow(2m..2m+1,h)
    const unsigned w0 = pk2(p[0], p[1]),   w1 = pk2(p[2], p[3]);
    const unsigned w2 = pk2(p[4], p[5]),   w3 = pk2(p[6], p[7]);
    const unsigned w4 = pk2(p[8], p[9]),   w5 = pk2(p[10], p[11]);
    const unsigned w6 = pk2(p[12], p[13]), w7 = pk2(p[14], p[15]);

    // permlane32_swap: out0 = {in0.lo | in1.lo->hi}, out1 = {in0.hi->lo | in1.hi}
    const uint2v a02 = __builtin_amdgcn_permlane32_swap(w0, w2, false, false);
    const uint2v a13 = __builtin_amdgcn_permlane32_swap(w1, w3, false, false);
    const uint2v a46 = __builtin_amdgcn_permlane32_swap(w4, w6, false, false);
    const uint2v a57 = __builtin_amdgcn_permlane32_swap(w5, w7, false, false);

    // PA frags: A[q = l31][key = kc*16 + 8*h32 + j]
    const short8 pa0 = __builtin_bit_cast(short8, (uintx4){a02[0], a13[0], a02[1], a13[1]});
    const short8 pa1 = __builtin_bit_cast(short8, (uintx4){a46[0], a57[0], a46[1], a57[1]});

    const int o0 = c ? v10 : v00;
    const int o1 = c ? v11 : v01;
    __builtin_amdgcn_s_setprio(1);      // T5: keep matrix pipe fed
    {
      const short8 bv0 = *(const short8*)&vsb[sel][o0];
      const short8 bv1 = *(const short8*)&vsb[sel][o1];
      Of0 = __builtin_amdgcn_mfma_f32_32x32x16_bf16(pa0, bv0, Of0, 0, 0, 0);
      Of0 = __builtin_amdgcn_mfma_f32_32x32x16_bf16(pa1, bv1, Of0, 0, 0, 0);
    }
    {
      const short8 bv0 = *(const short8*)&vsb[sel][o0 + 2048];
      const short8 bv1 = *(const short8*)&vsb[sel][o1 + 2048];
      Of1 = __builtin_amdgcn_mfma_f32_32x32x16_bf16(pa0, bv0, Of1, 0, 0, 0);
      Of1 = __builtin_amdgcn_mfma_f32_32x32x16_bf16(pa1, bv1, Of1, 0, 0, 0);
    }
    __builtin_amdgcn_s_setprio(0);
  };

  // --- 3-deep pipeline with counted vmcnt (waves 0-1: 3 VMEM/stage, 2-3: 2).
  stage(0, 0);
  stage(1, 1);
  if (w < 2) asm volatile("s_waitcnt vmcnt(3)" ::: "memory");
  else       asm volatile("s_waitcnt vmcnt(2)" ::: "memory");
  __builtin_amdgcn_s_barrier();

  for (int kt = 0; kt < 32; ++kt) {
    const int sel = kt % 3;
    if (kt < 31) stage(kt + 2, (kt + 2) % 3);
    chunk(0, false, sel);
    chunk(1, false, sel);
    if (kt < 31) {
      if (w < 2) asm volatile("s_waitcnt vmcnt(3)" ::: "memory");
      else       asm volatile("s_waitcnt vmcnt(2)" ::: "memory");
    } else {
      asm volatile("s_waitcnt vmcnt(0)" ::: "memory");
    }
    __builtin_amdgcn_s_barrier();
  }
  chunk(0, true, 2);  // tail tile 32 (32 % 3 == 2; keys 2048..2063 valid)

  // epilogue: combine key-half partial sums, transpose 1/l into C-layout
  lsum += __shfl_xor(lsum, 32);
  const float inv = 1.f / lsum;   // per q = l31, replicated across halves
#pragma unroll
  for (int r = 0; r < 16; ++r) {
    const int cr = (r & 3) + ((r >> 2) << 3) + (h32 << 2);  // crow(r,h32)
    const float invr = __shfl(inv, cr);
    const int qg = q0 + cr;
    float* op = out + (((size_t)(b * S_ + qg)) << 10) + (h << 6) + l31;
    op[0]  = Of0[r] * invr;
    op[32] = Of1[r] * invr;
  }
}

// ---------------------------------------------------------------------------
extern "C" void kernel_launch(void* const* d_in, const int* in_sizes, int n_in,
                              void* d_out, int out_size, void* d_ws, size_t ws_size,
                              hipStream_t stream) {
  (void)in_sizes; (void)n_in; (void)out_size; (void)ws_size;

  const float* x   = (const float*)d_in[0];
  const float* Wq  = (const float*)d_in[1];
  const float* bq  = (const float*)d_in[2];
  const float* Wqc = (const float*)d_in[3];
  const float* bqc = (const float*)d_in[4];
  const float* Wk  = (const float*)d_in[5];
  const float* bk  = (const float*)d_in[6];
  const float* Wkc = (const float*)d_in[7];
  const float* bkc = (const float*)d_in[8];
  const float* Wv  = (const float*)d_in[9];
  const float* bv  = (const float*)d_in[10];
  const float* Wvc = (const float*)d_in[11];
  const float* bvc = (const float*)d_in[12];
  float* out = (float*)d_out;

  // workspace layout (ushort units), total ~49 MB
  unsigned short* qb  = (unsigned short*)d_ws;                 // [MTOT][256]
  unsigned short* k2  = qb + (size_t)MTOT * 256;               // [64][NKT][64][16]
  unsigned short* v2  = k2 + (size_t)B_ * H_ * NKT * 1024;     // [64][NKT][4096]
  unsigned short* xh  = v2 + (size_t)B_ * H_ * NKT * 4096;     // [B*S][1024]
  unsigned short* wq2 = xh + (size_t)B_ * S_ * D_;             // [2][256][1024]
  unsigned short* wk2 = wq2 + (size_t)2 * 256 * 1024;
  unsigned short* wv2 = wk2 + (size_t)2 * 256 * 1024;          // [2][1024][1024]

  dim3 blk(256);

  // merged cast_x + weight transpose + V2 tail zero-fill (one dispatch)
  prep<<<dim3(2048 + 768 + 64), blk, 0, stream>>>(
      x, xh, Wq, Wqc, Wk, Wkc, Wv, Wvc, wq2, wk2, wv2, v2);

  // merged q+k+v CSS GEMM: nt 0-1 -> q (pre-scaled), 2-3 -> k (K2 tiled),
  // 4-11 -> v (V2 tiled)
  css_mfma2<<<dim3(12, 65), blk, 0, stream>>>(xh, wq2, bq, bqc, wk2, bk, bkc,
                                              wv2, bv, bvc, qb, k2, v2);

  attn_mfma<<<B_ * H_ * (S_ / 128), blk, 0, stream>>>(qb, k2, v2, out);
}